// Round 6
// baseline (292.841 us; speedup 1.0000x reference)
//
#include <hip/hip_runtime.h>
#include <hip/hip_bf16.h>
#include <math.h>

// Problem constants
#define BATCH 64
#define SEQ   512
#define DIM   768
#define NW    256              // MAX_WORDS
#define NT    (BATCH * NW)     // 16384 tokens
#define KDIM  1536             // 2*DIM
#define HID   256              // router hidden
#define NL    7                // num labels

// GEMM tiling
#define BM  64
#define BK  64
#define BKP 72                 // padded LDS row stride (bf16) -> 144 B
#define NKT (KDIM / BK)        // 24

typedef __bf16 bf16_t;
typedef bf16_t bf16x4 __attribute__((ext_vector_type(4)));
typedef bf16_t bf16x8 __attribute__((ext_vector_type(8)));
typedef float  f32x4  __attribute__((ext_vector_type(4)));

// ---------------------------------------------------------------------------
// Kernel 1: convert router_w1 (1536 x 256 fp32) -> bf16 K-major tiles
// w1t[kc][n][kk].  Grid 192.
// ---------------------------------------------------------------------------
__global__ __launch_bounds__(256) void convert_w1_kernel(
    const float* __restrict__ w1, bf16_t* __restrict__ w1t)
{
    int kc = blockIdx.x >> 3;
    int kg = blockIdx.x & 7;
    int n  = threadIdx.x;
    bf16x8 v;
    #pragma unroll
    for (int j = 0; j < 8; j++)
        v[j] = (bf16_t)w1[(size_t)(kc * 64 + kg * 8 + j) * HID + n];
    *(bf16x8*)(w1t + (size_t)kc * (HID * BK) + n * BK + kg * 8) = v;
}

// ---------------------------------------------------------------------------
// Kernel 2: starts table. starts[t][b][w] = lower_bound(ids[b], w); entry 256
// = SEQ. Grid 128.
// ---------------------------------------------------------------------------
__global__ __launch_bounds__(256) void starts_kernel(
    const int* __restrict__ idh, const int* __restrict__ idr,
    int* __restrict__ starts)
{
    int blk = blockIdx.x;
    int t = blk >> 6;
    int b = blk & 63;
    const int* ids = (t ? idr : idh) + b * SEQ;
    int w = threadIdx.x;
    int lo = 0, hi = SEQ;
    while (lo < hi) {
        int m = (lo + hi) >> 1;
        if (ids[m] < w) lo = m + 1; else hi = m;
    }
    int* row = starts + blk * 257;
    row[w] = lo;
    if (w == 0) row[256] = SEQ;
}

// ---------------------------------------------------------------------------
// Kernel 3: segment-mean align — ROW-STREAMING version.
// Task = (b, tensor, dim-slice of 256 floats, 32-word chunk) -> 3072 tasks,
// grid 768 x 256 (4 waves/block, independent).
// Each task walks rows [starts[w0], starts[w0+32]) sequentially in groups of
// 8: the 8 row loads + 1 id load are issued with AFFINE addresses before any
// word-boundary logic runs -> 8 KB in flight per wave, no data-dependent
// control flow in the load path. Words are emitted (mean, or zeros for gaps)
// as boundaries are crossed; each task owns a disjoint word range.
// ---------------------------------------------------------------------------
__global__ __launch_bounds__(256) void align_kernel(
    const float* __restrict__ hh, const float* __restrict__ hr,
    const int* __restrict__ idh, const int* __restrict__ idr,
    const int* __restrict__ starts, bf16_t* __restrict__ X)
{
    int tid  = threadIdx.x;
    int lane = tid & 63;
    int wv   = tid >> 6;
    int task = blockIdx.x * 4 + wv;        // 3072 tasks
    // task = ((b*2 + t)*3 + sl)*8 + q
    int q  = task & 7;                     // 32-word chunk
    int r3 = task >> 3;
    int sl = r3 % 3;                       // dim slice (256 floats)
    int bt = r3 / 3;
    int b  = bt >> 1;
    int t  = bt & 1;
    int w0 = q * 32;

    const int*   st   = starts + (t * 64 + b) * 257;
    const int*   ids  = (t ? idr : idh) + b * SEQ;
    const f32x4* base = (const f32x4*)((t ? hr : hh) + (size_t)b * SEQ * DIM) + sl * 64;
    bf16_t*      dst  = X + (size_t)b * NW * KDIM + t * DIM + sl * 256 + lane * 4;

    int sLo = st[w0];
    int sHi = st[w0 + 32];

    f32x4 acc = {0.f, 0.f, 0.f, 0.f};
    int   cnt = 0;
    int   w   = w0;

    for (int sb = sLo; sb < sHi; sb += 8) {
        // ---- batched loads, affine addresses, no branches ----
        int smax = sHi - 1;
        f32x4 v0 = base[(size_t)(sb     < smax ? sb     : smax) * 192 + lane];
        f32x4 v1 = base[(size_t)(sb + 1 < smax ? sb + 1 : smax) * 192 + lane];
        f32x4 v2 = base[(size_t)(sb + 2 < smax ? sb + 2 : smax) * 192 + lane];
        f32x4 v3 = base[(size_t)(sb + 3 < smax ? sb + 3 : smax) * 192 + lane];
        f32x4 v4 = base[(size_t)(sb + 4 < smax ? sb + 4 : smax) * 192 + lane];
        f32x4 v5 = base[(size_t)(sb + 5 < smax ? sb + 5 : smax) * 192 + lane];
        f32x4 v6 = base[(size_t)(sb + 6 < smax ? sb + 6 : smax) * 192 + lane];
        f32x4 v7 = base[(size_t)(sb + 7 < smax ? sb + 7 : smax) * 192 + lane];
        // 8 word-ids in one vector load (lanes 0..7), broadcast via readlane
        int myid = ids[(lane & 7) + sb < sHi ? (lane & 7) + sb : smax];

        f32x4 vv[8] = {v0, v1, v2, v3, v4, v5, v6, v7};
        #pragma unroll
        for (int j = 0; j < 8; j++) {
            int s = sb + j;
            if (s >= sHi) break;                       // uniform
            int wid = __builtin_amdgcn_readlane(myid, j);
            if (wid != w) {                            // uniform
                float inv = cnt > 0 ? 1.f / (float)cnt : 0.f;
                bf16x4 o;
                #pragma unroll
                for (int e = 0; e < 4; e++) o[e] = (bf16_t)(acc[e] * inv);
                *(bf16x4*)(dst + (size_t)w * KDIM) = o;
                for (int ww = w + 1; ww < wid; ww++) { // zero-gap words
                    bf16x4 z = {};
                    *(bf16x4*)(dst + (size_t)ww * KDIM) = z;
                }
                w = wid;
                acc = (f32x4){0.f, 0.f, 0.f, 0.f};
                cnt = 0;
            }
            acc += vv[j];
            cnt++;
        }
    }
    // tail: emit last word (zeros if task had no rows) + trailing gap words
    {
        float inv = cnt > 0 ? 1.f / (float)cnt : 0.f;
        bf16x4 o;
        #pragma unroll
        for (int e = 0; e < 4; e++) o[e] = (bf16_t)(acc[e] * inv);
        *(bf16x4*)(dst + (size_t)w * KDIM) = o;
        for (int ww = w + 1; ww < w0 + 32; ww++) {
            bf16x4 z = {};
            *(bf16x4*)(dst + (size_t)ww * KDIM) = z;
        }
    }
}

// ---------------------------------------------------------------------------
// Kernel 4: FUSED router GEMM (bf16 MFMA) + alpha + blend + head + l2.
// Grid 256 x 512 (8 waves = 2 token-groups x 4 col-groups). Block owns 64
// tokens. After the K-loop, LDS Ws region is reused for hw transposed.
// ---------------------------------------------------------------------------
__global__ __launch_bounds__(512) void fused_kernel(
    const bf16_t* __restrict__ X, const bf16_t* __restrict__ w1t,
    const float* __restrict__ b1, const float* __restrict__ w2,
    const float* __restrict__ b2, const float* __restrict__ hw,
    const float* __restrict__ hb, float* __restrict__ out)
{
    __shared__ __align__(16) bf16_t Xs[BM][BKP];      // 9216 B
    __shared__ __align__(16) bf16_t Ws[HID][BKP];     // 36864 B (reused for hw)
    __shared__ float alpha_acc[BM];
    __shared__ float alpha_s[BM];

    int tid   = threadIdx.x;
    int lane  = tid & 63;
    int wv    = tid >> 6;                  // 0..7
    int tg    = wv >> 2;                   // token group (0..1)
    int cg    = wv & 3;                    // col group (0..3)
    int row16 = lane & 15;
    int quad  = lane >> 4;
    int tok0  = blockIdx.x * BM;

    f32x4 acc[2][4];
    #pragma unroll
    for (int mi = 0; mi < 2; mi++)
        #pragma unroll
        for (int ni = 0; ni < 4; ni++)
            acc[mi][ni] = (f32x4){0.f, 0.f, 0.f, 0.f};

    int xr = tid >> 3;                     // 0..63
    int xc = tid & 7;

    for (int kc = 0; kc < NKT; kc++) {
        {   // X tile: 64 x 64 bf16 = 512 chunks, 1/thread
            const uint4* src = (const uint4*)(X + (size_t)(tok0 + xr) * KDIM + kc * BK + xc * 8);
            *(uint4*)(&Xs[xr][xc * 8]) = *src;
        }
        {   // W tile: 256 x 64 bf16 = 2048 chunks, 4/thread, coalesced
            const uint4* srcb = (const uint4*)(w1t + (size_t)kc * (HID * BK));
            #pragma unroll
            for (int i = 0; i < 4; i++) {
                int cidx = tid + i * 512;
                *(uint4*)(&Ws[cidx >> 3][(cidx & 7) * 8]) = srcb[cidx];
            }
        }
        __syncthreads();
        #pragma unroll
        for (int kk2 = 0; kk2 < 2; kk2++) {
            bf16x8 af[2], bfg[4];
            #pragma unroll
            for (int mi = 0; mi < 2; mi++)
                af[mi] = *(const bf16x8*)(&Xs[tg * 32 + mi * 16 + row16][kk2 * 32 + quad * 8]);
            #pragma unroll
            for (int ni = 0; ni < 4; ni++)
                bfg[ni] = *(const bf16x8*)(&Ws[cg * 64 + ni * 16 + row16][kk2 * 32 + quad * 8]);
            #pragma unroll
            for (int mi = 0; mi < 2; mi++)
                #pragma unroll
                for (int ni = 0; ni < 4; ni++)
                    acc[mi][ni] = __builtin_amdgcn_mfma_f32_16x16x32_bf16(
                        af[mi], bfg[ni], acc[mi][ni], 0, 0, 0);
        }
        __syncthreads();
    }

    // ---- alpha = sigmoid( relu(hdn + b1) . w2 + b2 ) ----------------------
    float w2v[4], b1v[4];
    #pragma unroll
    for (int ni = 0; ni < 4; ni++) {
        int col = cg * 64 + ni * 16 + row16;
        w2v[ni] = w2[col];
        b1v[ni] = b1[col];
    }
    if (tid < BM) alpha_acc[tid] = 0.f;
    __syncthreads();

    #pragma unroll
    for (int mi = 0; mi < 2; mi++) {
        #pragma unroll
        for (int r = 0; r < 4; r++) {
            float p = 0.f;
            #pragma unroll
            for (int ni = 0; ni < 4; ni++) {
                float v = acc[mi][ni][r] + b1v[ni];
                v = v > 0.f ? v : 0.f;
                p += v * w2v[ni];
            }
            p += __shfl_xor(p, 1);
            p += __shfl_xor(p, 2);
            p += __shfl_xor(p, 4);
            p += __shfl_xor(p, 8);
            if (row16 == 0)
                atomicAdd(&alpha_acc[tg * 32 + mi * 16 + quad * 4 + r], p);
        }
    }
    __syncthreads();
    if (tid < BM) {
        float a = 1.f / (1.f + expf(-(alpha_acc[tid] + b2[0])));
        alpha_s[tid] = a;
        out[(size_t)NT * NL + tok0 + tid] = a;
    }

    // ---- reuse Ws LDS for hw transposed [l][d] ---------------------------
    float* hws = (float*)&Ws[0][0];        // 21504 B <= 36864 B
    __syncthreads();                       // alpha_s ready; Ws no longer needed
    for (int i = tid; i < DIM * NL; i += 512) {
        int d = i / NL, l = i - d * NL;    // source [d][l]
        hws[l * DIM + d] = hw[i];
    }
    __syncthreads();

    // ---- blend + head + l2: wave handles 8 tokens (lane-group of 8) ------
    int g   = lane >> 3;
    int u   = lane & 7;
    int tok = tok0 + wv * 8 + g;

    float a = alpha_s[wv * 8 + g];
    const bf16_t* xrow = X + (size_t)tok * KDIM;   // L2-warm (staged above)

    float lg[NL] = {0.f, 0.f, 0.f, 0.f, 0.f, 0.f, 0.f};
    float l2 = 0.f;

    #pragma unroll
    for (int k = 0; k < 12; k++) {
        int d0 = (k * 8 + u) * 8;
        bf16x8 hp = *(const bf16x8*)(xrow + d0);
        bf16x8 rp = *(const bf16x8*)(xrow + DIM + d0);
        float bl[8];
        #pragma unroll
        for (int e = 0; e < 8; e++) {
            float hhv = (float)hp[e];
            float hrv = (float)rp[e];
            float df  = hhv - hrv;
            bl[e] = fmaf(a, df, hrv);
            l2 = fmaf(df, df, l2);
        }
        #pragma unroll
        for (int l = 0; l < NL; l++) {
            f32x4 wA = *(const f32x4*)(&hws[l * DIM + d0]);
            f32x4 wB = *(const f32x4*)(&hws[l * DIM + d0 + 4]);
            lg[l] += bl[0]*wA[0] + bl[1]*wA[1] + bl[2]*wA[2] + bl[3]*wA[3]
                   + bl[4]*wB[0] + bl[5]*wB[1] + bl[6]*wB[2] + bl[7]*wB[3];
        }
    }

    #pragma unroll
    for (int off = 1; off < 8; off <<= 1) {
        #pragma unroll
        for (int l = 0; l < NL; l++) lg[l] += __shfl_xor(lg[l], off);
        l2 += __shfl_xor(l2, off);
    }

    if (u < NL) {
        float v = (u == 0) ? lg[0] : (u == 1) ? lg[1] : (u == 2) ? lg[2]
                : (u == 3) ? lg[3] : (u == 4) ? lg[4] : (u == 5) ? lg[5] : lg[6];
        out[(size_t)tok * NL + u] = v + hb[u];
    } else {
        out[(size_t)NT * NL + NT + tok] = sqrtf(l2);
    }
}

// ---------------------------------------------------------------------------
extern "C" void kernel_launch(void* const* d_in, const int* in_sizes, int n_in,
                              void* d_out, int out_size, void* d_ws, size_t ws_size,
                              hipStream_t stream)
{
    const float* hh  = (const float*)d_in[0];
    const float* hr  = (const float*)d_in[1];
    const int*   idh = (const int*)d_in[2];
    const int*   idr = (const int*)d_in[3];
    const float* w1  = (const float*)d_in[5];
    const float* b1  = (const float*)d_in[6];
    const float* w2  = (const float*)d_in[7];
    const float* b2  = (const float*)d_in[8];
    const float* hw  = (const float*)d_in[9];
    const float* hb  = (const float*)d_in[10];
    float* out = (float*)d_out;

    bf16_t* X      = (bf16_t*)d_ws;                        // 50.33 MB
    bf16_t* w1t    = X + (size_t)NT * KDIM;                // 0.79 MB (tiled)
    int*    starts = (int*)(w1t + (size_t)NKT * HID * BK); // 263 KB

    convert_w1_kernel<<<192, 256, 0, stream>>>(w1, w1t);
    starts_kernel<<<128, 256, 0, stream>>>(idh, idr, starts);
    align_kernel<<<768, 256, 0, stream>>>(hh, hr, idh, idr, starts, X);
    fused_kernel<<<NT / BM, 512, 0, stream>>>(X, w1t, b1, w2, b2, hw, hb, out);
}